// Round 6
// baseline (272.198 us; speedup 1.0000x reference)
//
#include <hip/hip_runtime.h>

typedef unsigned short u16;
typedef __attribute__((ext_vector_type(8))) __bf16 bf16x8;
typedef __attribute__((ext_vector_type(4))) _Float16 f16x4;
typedef __attribute__((ext_vector_type(8))) _Float16 f16x8;
typedef __attribute__((ext_vector_type(4))) float f32x4;

#define BB 4
#define SS 1024
#define DD 2048
#define HH 32
#define KVHN 8
#define HDIM 64

__device__ __forceinline__ u16 f2b(float f) {
    union { float f; unsigned u; } v; v.f = f;
    unsigned r = v.u + 0x7FFFu + ((v.u >> 16) & 1u);
    return (u16)(r >> 16);
}
__device__ __forceinline__ float b2f(u16 h) {
    union { unsigned u; float f; } v; v.u = ((unsigned)h) << 16; return v.f;
}

__device__ __forceinline__ f32x4 mfma16(bf16x8 a, bf16x8 b, f32x4 c) {
    return __builtin_amdgcn_mfma_f32_16x16x32_bf16(a, b, c, 0, 0, 0);
}
__device__ __forceinline__ f32x4 mfma16h(f16x8 a, f16x8 b, f32x4 c) {
    return __builtin_amdgcn_mfma_f32_16x16x32_f16(a, b, c, 0, 0, 0);
}

__device__ __forceinline__ void async_cp16(const void* g, void* l) {
    __builtin_amdgcn_global_load_lds((__attribute__((address_space(1))) void*)g,
                                     (__attribute__((address_space(3))) void*)l,
                                     16, 0, 0);
}

// raw barrier WITHOUT the compiler's vmcnt(0) drain
__device__ __forceinline__ void block_sync() {
    asm volatile("" ::: "memory");
    __builtin_amdgcn_s_barrier();
    asm volatile("" ::: "memory");
}

// pack 8 floats -> f16x8 via v_cvt_pkrtz
__device__ __forceinline__ f16x8 pack8_f16(const float* p) {
    union { unsigned u[4]; f16x8 v; } pu;
    pu.u[0] = __builtin_bit_cast(unsigned, __builtin_amdgcn_cvt_pkrtz(p[0], p[1]));
    pu.u[1] = __builtin_bit_cast(unsigned, __builtin_amdgcn_cvt_pkrtz(p[2], p[3]));
    pu.u[2] = __builtin_bit_cast(unsigned, __builtin_amdgcn_cvt_pkrtz(p[4], p[5]));
    pu.u[3] = __builtin_bit_cast(unsigned, __builtin_amdgcn_cvt_pkrtz(p[6], p[7]));
    return pu.v;
}

// ---------------- cast x (fp32 -> bf16) ----------------
__global__ __launch_bounds__(256) void cast_x_kernel(const float* __restrict__ x,
                                                     u16* __restrict__ xb) {
    int i = (blockIdx.x * 256 + threadIdx.x) * 4;
    float4 v = *(const float4*)(x + i);
    unsigned r0 = (unsigned)f2b(v.x) | ((unsigned)f2b(v.y) << 16);
    unsigned r1 = (unsigned)f2b(v.z) | ((unsigned)f2b(v.w) << 16);
    *(uint2*)(xb + i) = make_uint2(r0, r1);
}

// ---------------- all weight transposes in one launch ----------------
__global__ __launch_bounds__(256) void wtrans_all_kernel(const float* __restrict__ Wq,
                                                         const float* __restrict__ Wk,
                                                         const float* __restrict__ Wv,
                                                         const float* __restrict__ Wo,
                                                         u16* __restrict__ Wqkvt,
                                                         u16* __restrict__ Wot) {
    __shared__ float tile[32][33];
    int z = blockIdx.z;
    const float* W = (z == 0) ? Wq : (z == 1) ? Wk : (z == 2) ? Wv : Wo;
    int N = (z == 1 || z == 2) ? 512 : 2048;
    int n_off = (z == 1) ? 2048 : (z == 2) ? 2560 : 0;
    u16* Wt = (z == 3) ? Wot : Wqkvt;
    int n0 = blockIdx.x * 32;
    if (n0 >= N) return;
    int k0 = blockIdx.y * 32;
    int tid = threadIdx.x;
    int nj = tid & 31;
    int ki = tid >> 5;
#pragma unroll
    for (int it = 0; it < 4; it++) {
        int kk = it * 8 + ki;
        tile[kk][nj] = W[(size_t)(k0 + kk) * N + n0 + nj];
    }
    __syncthreads();
#pragma unroll
    for (int it = 0; it < 4; it++) {
        int nn = it * 8 + ki;
        Wt[(size_t)(n0 + nn + n_off) * 2048 + k0 + nj] = f2b(tile[nj][nn]);
    }
}

// ============================================================================
// GEMM (qkv): C[4096][3072](bf16) = A[4096][2048] * Bt[3072][2048]^T
// 8-phase quadrant template, CORRECTED LEDGER (round-5 race fixed).
// 256x256, BK=64, 8 waves (2Mx4N, wave 128x64). LDS/buf: A halves @0/@8192,
// B halves @16384/@24576; 2 bufs = 128 KiB. Phase = one C-quadrant x K=64 =
// 16 MFMA. Reads/phase: 12,4,8,0 (b0/b1 frag register reuse at ph4/ph3).
// TRUE deaths (reads spread over both halves by wave m/n split):
//   buf0.B after ph2, buf0.A after ph3, buf1.B after ph6, buf1.A after ph7.
// Stage slots (1 unit = 16KB = 2 loads per phase), all strictly post-death:
//   ph1: buf1.A0(b)   ph2: buf1.A1(b)   ph3: buf0.B0(a+2) ph4: buf0.B1(a+2)
//   ph5: buf0.A0(a+2) ph6: buf0.A1(a+2) ph7: buf1.B0(b+2) ph8: buf1.B1(b+2)
// vmcnt(4)@ph4 certifies tile b (carried ph7/8-prev + ph1/2);
// vmcnt(4)@ph8 certifies tile a+2 (ph3..ph6); leaves ph7/8 in flight.
// No same-region same-phase staging; every stage target's last read was
// drained by that reader's lgkmcnt(0) + phase-end barrier before issue.
// ============================================================================
__global__ __launch_bounds__(512, 2) void gemm_qkv(const u16* __restrict__ A,
                                                   const u16* __restrict__ Bt,
                                                   u16* __restrict__ C) {
    __shared__ __align__(16) u16 Ls[2][32768];
    const int tid = threadIdx.x;
    const int lane = tid & 63;
    const int w = tid >> 6;

    // 192 blocks; XCD owns 4m x 6n super-tile
    const int bid = blockIdx.x;
    const int xcd = bid & 7;
    const int loc = bid >> 3;
    const int mt = (xcd & 3) * 4 + (loc & 3);    // 0..15
    const int nt = (xcd >> 2) * 6 + (loc >> 2);  // 0..11
    const int m0 = mt * 256;
    const int n0 = nt * 256;

    const int wm_h = w >> 2;        // wave m-half (0/1)
    const int wn = (w & 3) * 64;    // wave n-offset
    const int lr = lane & 15;
    const int lg = lane >> 4;

    // staging source (pre-swizzled k-slot): row w*8+sr, slot (lane&7)^(sr&7)
    const int sr = lane >> 3;
    const int sl = (lane & 7) ^ (sr & 7);
    const u16* pA = A + (size_t)(m0 + w * 8 + sr) * 2048 + sl * 8;
    const u16* pB = Bt + (size_t)(n0 + w * 8 + sr) * 2048 + sl * 8;

#define STA(buf_, h_, kt_)                                                               \
    {                                                                                    \
        async_cp16(pA + (size_t)((h_) * 128) * 2048 + (kt_) * 64, &Ls[buf_][(h_) * 8192 + w * 512]);            \
        async_cp16(pA + (size_t)((h_) * 128 + 64) * 2048 + (kt_) * 64, &Ls[buf_][(h_) * 8192 + 4096 + w * 512]); \
    }
#define STB(buf_, h_, kt_)                                                               \
    {                                                                                    \
        async_cp16(pB + (size_t)((h_) * 128) * 2048 + (kt_) * 64, &Ls[buf_][16384 + (h_) * 8192 + w * 512]);            \
        async_cp16(pB + (size_t)((h_) * 128 + 64) * 2048 + (kt_) * 64, &Ls[buf_][16384 + (h_) * 8192 + 4096 + w * 512]); \
    }

    f32x4 acc[8][4];
    const f32x4 zero4 = {0.f, 0.f, 0.f, 0.f};
#pragma unroll
    for (int i = 0; i < 8; i++)
#pragma unroll
        for (int j = 0; j < 4; j++) acc[i][j] = zero4;

    bf16x8 af[8], b0[4], b1[4];

#define LDA(mh_, buf_)                                                                   \
    _Pragma("unroll") for (int mi = 0; mi < 4; mi++) _Pragma("unroll") for (int ks = 0; ks < 2; ks++) { \
        int rh = (mh_) * 64 + mi * 16 + lr;                                              \
        af[mi * 2 + ks] = *(const bf16x8*)(&Ls[buf_][wm_h * 8192 + rh * 64 + (((ks * 4 + lg) ^ (lr & 7)) * 8)]); \
    }
#define LDB(dst_, nh_, buf_)                                                             \
    _Pragma("unroll") for (int ni = 0; ni < 2; ni++) _Pragma("unroll") for (int ks = 0; ks < 2; ks++) { \
        int rowb = wn + (nh_) * 32 + ni * 16 + lr;                                       \
        dst_[ni * 2 + ks] = *(const bf16x8*)(&Ls[buf_][16384 + (rowb >> 7) * 8192 + (rowb & 127) * 64 + (((ks * 4 + lg) ^ (lr & 7)) * 8)]); \
    }
#define QMM(mh_, nh_, bb_)                                                               \
    __builtin_amdgcn_s_setprio(1);                                                       \
    _Pragma("unroll") for (int mi = 0; mi < 4; mi++) _Pragma("unroll") for (int ni = 0; ni < 2; ni++) { \
        acc[(mh_) * 4 + mi][(nh_) * 2 + ni] = mfma16(af[mi * 2 + 0], bb_[ni * 2 + 0], acc[(mh_) * 4 + mi][(nh_) * 2 + ni]); \
        acc[(mh_) * 4 + mi][(nh_) * 2 + ni] = mfma16(af[mi * 2 + 1], bb_[ni * 2 + 1], acc[(mh_) * 4 + mi][(nh_) * 2 + ni]); \
    }                                                                                    \
    __builtin_amdgcn_s_setprio(0);
#define WAITLDS                                                                          \
    asm volatile("s_waitcnt lgkmcnt(0)" ::: "memory");                                   \
    __builtin_amdgcn_sched_barrier(0);

    // prologue: tile0 full (buf0) + tile1 {B0,B1} (buf1); iter0 ph1/2 stage tile1 A0/A1
    STA(0, 0, 0); STA(0, 1, 0); STB(0, 0, 0); STB(0, 1, 0);
    STB(1, 0, 1); STB(1, 1, 1);
    asm volatile("s_waitcnt vmcnt(0)" ::: "memory");
    block_sync();

#pragma unroll 1
    for (int I = 0; I < 16; ++I) {
        const int tb = 2 * I + 1;
        const int ta2 = (2 * I + 2) & 31;  // tail wrap: redundant, never read
        const int tb2 = (2 * I + 3) & 31;

        // ph1: Q(m0,n0) of a [buf0]; stage buf1.A0(b) [buf1.A dead since prev ph7]
        LDA(0, 0); LDB(b0, 0, 0);
        STA(1, 0, tb);
        block_sync(); WAITLDS;
        QMM(0, 0, b0);
        block_sync();
        // ph2: Q(m0,n1); stage buf1.A1(b)
        LDB(b1, 1, 0);
        STA(1, 1, tb);
        block_sync(); WAITLDS;
        QMM(0, 1, b1);
        block_sync();
        // ph3: Q(m1,n1); stage buf0.B0(a+2) [buf0.B dead since ph2]
        LDA(1, 0);
        STB(0, 0, ta2);
        block_sync(); WAITLDS;
        QMM(1, 1, b1);
        block_sync();
        // ph4: Q(m1,n0) (b0 reg reuse); stage buf0.B1(a+2); certify tile b
        STB(0, 1, ta2);
        block_sync(); WAITLDS;
        QMM(1, 0, b0);
        asm volatile("s_waitcnt vmcnt(4)" ::: "memory");
        block_sync();

        // ph5: Q(m0,n0) of b [buf1]; stage buf0.A0(a+2) [buf0.A dead since ph3]
        LDA(0, 1); LDB(b0, 0, 1);
        STA(0, 0, ta2);
        block_sync(); WAITLDS;
        QMM(0, 0, b0);
        block_sync();
        // ph6: Q(m0,n1); stage buf0.A1(a+2)
        LDB(b1, 1, 1);
        STA(0, 1, ta2);
        block_sync(); WAITLDS;
        QMM(0, 1, b1);
        block_sync();
        // ph7: Q(m1,n1); stage buf1.B0(b+2) [buf1.B dead since ph6]
        LDA(1, 1);
        STB(1, 0, tb2);
        block_sync(); WAITLDS;
        QMM(1, 1, b1);
        block_sync();
        // ph8: Q(m1,n0) (b0 reg reuse); stage buf1.B1(b+2); certify tile a+2
        STB(1, 1, tb2);
        block_sync(); WAITLDS;
        QMM(1, 0, b0);
        asm volatile("s_waitcnt vmcnt(4)" ::: "memory");
        block_sync();
    }
    asm volatile("s_waitcnt vmcnt(0)" ::: "memory");

    const int lq = lg * 4;
    const int wm = wm_h * 128;
#pragma unroll
    for (int mi = 0; mi < 8; mi++)
#pragma unroll
        for (int ni = 0; ni < 4; ni++)
#pragma unroll
            for (int i = 0; i < 4; i++) {
                int r = m0 + wm + mi * 16 + lq + i;
                int c = n0 + wn + ni * 16 + lr;
                C[(size_t)r * 3072 + c] = f2b(acc[mi][ni][i]);
            }
#undef STA
#undef STB
#undef LDA
#undef LDB
#undef QMM
#undef WAITLDS
}

// ============================================================================
// GEMM (out): C[4096][2048](f32) = A[4096][2048](bf16) * Bt[2048][2048]^T
// Round-4 VERIFIED version (k-slice 2-phase, vmcnt(3)). Kept unchanged this
// round to isolate the qkv template A/B.
// ============================================================================
__global__ __launch_bounds__(512, 2) void gemm_out(const u16* __restrict__ A,
                                                   const u16* __restrict__ Bt,
                                                   float* __restrict__ C) {
    __shared__ __align__(16) u16 Ls[2][24576];  // A ks0|ks1 @0/8192, B ks0|ks1 @16384/20480
    const int tid = threadIdx.x;
    const int lane = tid & 63;
    const int w = tid >> 6;

    const int bid = blockIdx.x;
    const int xcd = bid & 7;
    const int loc = bid >> 3;            // 0..31
    const int mt = (xcd & 3) * 4 + (loc & 3);    // 0..15
    const int nt = (xcd >> 2) * 8 + (loc >> 2);  // 0..15
    const int m0 = mt * 256;
    const int n0 = nt * 128;

    const int wm = (w >> 2) * 128;
    const int wn = (w & 3) * 32;
    const int lr = lane & 15;
    const int lg = lane >> 4;

    const int row0 = tid >> 2;
    const int g = tid & 3;
    const int sg = g ^ ((row0 >> 1) & 3);
    const u16* pA0 = A + (size_t)(m0 + row0) * 2048 + sg * 8;
    const u16* pA1 = pA0 + (size_t)128 * 2048;
    const u16* pB0 = Bt + (size_t)(n0 + row0) * 2048 + sg * 8;  // B chunk: 128 rows, 1 load/thr

#define OSTA(buf_, ks_, T_)                                                     \
    {                                                                           \
        async_cp16(pA0 + (T_) * 64 + (ks_) * 32, &Ls[buf_][(ks_) * 8192 + w * 512]);        \
        async_cp16(pA1 + (T_) * 64 + (ks_) * 32, &Ls[buf_][(ks_) * 8192 + 4096 + w * 512]); \
    }
#define OSTB(buf_, ks_, T_)                                                     \
    {                                                                           \
        async_cp16(pB0 + (T_) * 64 + (ks_) * 32, &Ls[buf_][16384 + (ks_) * 4096 + w * 512]); \
    }

    f32x4 acc[8][2];
    const f32x4 zero4 = {0.f, 0.f, 0.f, 0.f};
#pragma unroll
    for (int i = 0; i < 8; i++)
#pragma unroll
        for (int j = 0; j < 2; j++) acc[i][j] = zero4;

    bf16x8 af[8], bfr[2];

#define OLDA(ks_)                                                               \
    _Pragma("unroll") for (int mi = 0; mi < 8; mi++) {                          \
        int r_ = wm + mi * 16 + lr;                                             \
        af[mi] = *(const bf16x8*)(&Ls[cur][(ks_) * 8192 + r_ * 32 + ((lg ^ ((r_ >> 1) & 3)) * 8)]); \
    }
#define OLDB(ks_)                                                               \
    _Pragma("unroll") for (int ni = 0; ni < 2; ni++) {                          \
        int r_ = wn + ni * 16 + lr;                                             \
        bfr[ni] = *(const bf16x8*)(&Ls[cur][16384 + (ks_) * 4096 + r_ * 32 + ((lg ^ ((r_ >> 1) & 3)) * 8)]); \
    }
#define OMM                                                                     \
    __builtin_amdgcn_s_setprio(1);                                              \
    _Pragma("unroll") for (int mi = 0; mi < 8; mi++) _Pragma("unroll") for (int ni = 0; ni < 2; ni++) { \
        acc[mi][ni] = mfma16(af[mi], bfr[ni], acc[mi][ni]);                     \
    }                                                                           \
    __builtin_amdgcn_s_setprio(0);
#define OWAITMM                                                                 \
    asm volatile("s_waitcnt lgkmcnt(0)" ::: "memory");                          \
    __builtin_amdgcn_sched_barrier(0);

    // prologue: tile0 full + tile1-ks0 (9 loads); vmcnt(3): tile0's 6 landed.
    OSTA(0, 0, 0); OSTB(0, 0, 0); OSTA(0, 1, 0); OSTB(0, 1, 0);
    OSTA(1, 0, 1); OSTB(1, 0, 1);
    asm volatile("s_waitcnt vmcnt(3)" ::: "memory");
    block_sync();

#pragma unroll 2
    for (int T = 0; T < 32; ++T) {
        const int cur = T & 1;
        const int oth = cur ^ 1;
        const int Tp1 = (T + 1) & 31;
        const int Tp2 = (T + 2) & 31;

        // ---- phase 1: ks0 ----
        OLDA(0); OLDB(0);
        OSTA(oth, 1, Tp1); OSTB(oth, 1, Tp1);   // tile T-1 ks1 regions (dead)
        block_sync(); OWAITMM;
        OMM;
        block_sync();
        // ---- phase 2: ks1 ----
        OLDA(1); OLDB(1);
        OSTA(cur, 0, Tp2); OSTB(cur, 0, Tp2);   // tile T ks0 regions (read ph1, drained)
        block_sync(); OWAITMM;
        OMM;
        asm volatile("s_waitcnt vmcnt(3)" ::: "memory");  // certify tile T+1
        block_sync();
    }
    asm volatile("s_waitcnt vmcnt(0)" ::: "memory");

    const int lq = lg * 4;
#pragma unroll
    for (int mi = 0; mi < 8; mi++)
#pragma unroll
        for (int ni = 0; ni < 2; ni++)
#pragma unroll
            for (int i = 0; i < 4; i++) {
                int r = m0 + wm + mi * 16 + lq + i;
                int c = n0 + wn + ni * 16 + lr;
                C[(size_t)r * 2048 + c] = acc[mi][ni][i];
            }
#undef OSTA
#undef OSTB
#undef OLDA
#undef OLDB
#undef OMM
#undef OWAITMM
}

// ---------------- RoPE + reshape.  Q pre-scaled by 0.125*log2(e).
// K rows permuted within each 32-seq block so QK S-tiles emit the K=32 PV B-layout:
// row = (s&~31) + (rr>=4)*16 + ((s>>3)&3)*4 + (rr&3), rr = s&7.
__global__ __launch_bounds__(256) void rope_kernel(const u16* __restrict__ QKV,
                                                   const float* __restrict__ cosT,
                                                   const float* __restrict__ sinT,
                                                   u16* __restrict__ Qh,
                                                   u16* __restrict__ Kh) {
    const float QSC = 0.125f * 1.44269504088896f;
    int idx = blockIdx.x * 256 + threadIdx.x;
    int d = idx & 31;
    int t = idx >> 5;
    int hh = t % 40;
    int row = t / 40;
    int s = row & (SS - 1);
    int b = row >> 10;
    float c = cosT[s * HDIM + d];
    float sn = sinT[s * HDIM + d];
    if (hh < 32) {
        const u16* src = QKV + (size_t)row * 3072 + hh * 64 + d;
        float x1 = b2f(src[0]), x2 = b2f(src[32]);
        u16* dst = Qh + ((size_t)(b * HH + hh) * SS + s) * 64 + d;
        dst[0] = f2b((x1 * c - x2 * sn) * QSC);
        dst[32] = f2b((x2 * c + x1 * sn) * QSC);
    } else {
        int g = hh - 32;
        const u16* src = QKV + (size_t)row * 3072 + 2048 + g * 64 + d;
        float x1 = b2f(src[0]), x2 = b2f(src[32]);
        int rr = s & 7;
        int kpos = (s & ~31) + ((rr >= 4) ? 16 : 0) + ((s >> 3) & 3) * 4 + (rr & 3);
        u16* dst = Kh + ((size_t)(b * KVHN + g) * SS + kpos) * 64 + d;
        dst[0] = f2b(x1 * c - x2 * sn);
        dst[32] = f2b(x2 * c + x1 * sn);
    }
}

// ---------------- V transpose: QKV bf16 -> Vt[B][KVH][64][S] f16 (identity kv order) ----------------
__global__ __launch_bounds__(256) void vtrans_kernel(const u16* __restrict__ QKV,
                                                     u16* __restrict__ Vt) {
    __shared__ u16 tile[64][65];
    int blk = blockIdx.x;
    int st = blk & 15;
    int t2 = blk >> 4;
    int g = t2 & 7;
    int b = t2 >> 3;
    int tid = threadIdx.x;
    int cj = tid & 63;
    int ri = tid >> 6;
    const u16* src = QKV + ((size_t)(b * SS + st * 64)) * 3072 + 2560 + g * 64;
#pragma unroll
    for (int it = 0; it < 16; it++) {
        int s_i = it * 4 + ri;
        tile[s_i][cj] = src[(size_t)s_i * 3072 + cj];
    }
    __syncthreads();
    u16* dst = Vt + ((size_t)(b * KVHN + g) * HDIM) * SS + st * 64;
#pragma unroll
    for (int it = 0; it < 16; it++) {
        int hd_i = it * 4 + ri;
        _Float16 hv = (_Float16)b2f(tile[cj][hd_i]);
        union { _Float16 h; u16 u; } cv; cv.h = hv;
        dst[(size_t)hd_i * SS + cj] = cv.u;
    }
}

// ---------------- Flash attention: 32 q-rows/block, K=32 PV, LDS-staged K/V ----------------
// 1-D grid 1024, 256 threads. XCD-aware decode: each XCD owns 4 (b,g) KV-sets (1 MB, L2-fit).
__global__ __launch_bounds__(256, 4) void flash_kernel(const u16* __restrict__ Qh,
                                                       const u16* __restrict__ Kh,
                                                       const u16* __restrict__ Vt,
                                                       u16* __restrict__ Attn) {
    __shared__ __align__(16) u16 Kls[2][4096];
    __shared__ __align__(16) u16 Vls[2][4096];
    const int tid = threadIdx.x;
    const int lane = tid & 63;
    const int w = tid >> 6;
    const int bid = blockIdx.x;
    const int gbp = ((bid & 7) << 2) | ((bid >> 3) & 3);  // XCD-chunked (b,g) pair
    const int qt = bid >> 5;
    const int g = gbp & 7;
    const int b = gbp >> 3;
    const int h = g * 4 + w;
    const int lr = lane & 15;
    const int lg = lane >> 4;
    const int lk8 = lg * 8;
    const int lq = lg * 4;

    const u16* Qbase = Qh + ((size_t)(b * HH + h) * SS + qt * 32) * HDIM;
    bf16x8 qb[2][2];
#pragma unroll
    for (int j = 0; j < 2; j++) {
        qb[j][0] = *(const bf16x8*)(Qbase + (size_t)(j * 16 + lr) * HDIM + lk8);
        qb[j][1] = *(const bf16x8*)(Qbase + (size_t)(j * 16 + lr) * HDIM + 32 + lk8);
    }

    const u16* Kbase = Kh + (size_t)(b * KVHN + g) * SS * HDIM;
    const u16* Vbase = Vt + (size_t)(b * KVHN + g) * HDIM * SS;

    const int r0 = tid >> 3;
    const int c0 = tid & 7;

    const f32x4 zero4 = {0.f, 0.f, 0.f, 0.f};
    const f32x4 initS = {-4.f, -4.f, -4.f, -4.f};
    f32x4 o[2][4];
    float lsum[2] = {0.f, 0.f};
#pragma unroll
    for (int j = 0; j < 2; j++)
#pragma unroll
        for (int i = 0; i < 4; i++) o[j][i] = zero4;

#define STAGE(kt, p)                                                              \
    {                                                                             \
        _Pragma("unroll") for (int sh = 0; sh < 2; sh++) {                        \
            int rr = r0 + sh * 32;                                                \
            int cs = c0 ^ (rr & 7);                                              \
            async_cp16(Kbase + (size_t)((kt) + rr) * HDIM + cs * 8,               \
                       &Kls[p][sh * 2048 + w * 512]);                             \
            async_cp16(Vbase + (size_t)rr * SS + (kt) + cs * 8,                   \
                       &Vls[p][sh * 2048 + w * 512]);                             \
        }                                                                         \
    }

    STAGE(0, 0);
    __syncthreads();

    for (int t = 0; t < 16; t++) {
        const int p = t & 1;
        if (t < 15) STAGE((t + 1) * 64, p ^ 1);

#pragma unroll
        for (int c = 0; c < 2; c++) {  // two 32-kv chunks per 64-tile
            f32x4 s[2][2];  // [half][j]
#pragma unroll
            for (int halfi = 0; halfi < 2; halfi++) {
                const int R = c * 32 + halfi * 16 + lr;
                const u16* kr = &Kls[p][R * 64];
                bf16x8 kb0 = *(const bf16x8*)(kr + ((lg ^ (R & 7)) * 8));
                bf16x8 kb1 = *(const bf16x8*)(kr + (((4 + lg) ^ (R & 7)) * 8));
#pragma unroll
                for (int j = 0; j < 2; j++) {
                    f32x4 a = initS;
                    a = mfma16(kb0, qb[j][0], a);
                    a = mfma16(kb1, qb[j][1], a);
                    s[halfi][j] = a;
                }
            }

            f16x8 va[4];
#pragma unroll
            for (int hdt = 0; hdt < 4; hdt++) {
                const int R2 = hdt * 16 + lr;
                va[hdt] = *(const f16x8*)(&Vls[p][R2 * 64 + (((c * 4 + lg) ^ (R2 & 7)) * 8)]);
            }

#pragma unroll
            for (int j = 0; j < 2; j++) {
                float pv[8];
#pragma unroll
                for (int r = 0; r < 4; r++) {
                    pv[r] = __builtin_amdgcn_exp2f(s[0][j][r]);
                    pv[4 + r] = __builtin_amdgcn_exp2f(s[1][j][r]);
                }
                lsum[j] += ((pv[0] + pv[1]) + (pv[2] + pv[3])) +
                           ((pv[4] + pv[5]) + (pv[6] + pv[7]));
                f16x8 pb = pack8_f16(pv);
#pragma unroll
                for (int hdt = 0; hdt < 4; hdt++)
                    o[j][hdt] = mfma16h(va[hdt], pb, o[j][hdt]);
            }
        }
        __syncthreads();
    }

#pragma unroll
    for (int j = 0; j < 2; j++) {
        float su = lsum[j];
        su += __shfl_xor(su, 16);
        su += __shfl_xor(su, 32);
        float inv = 1.f / su;
        u16* Ob = Attn + ((size_t)(b * SS + qt * 32 + j * 16 + lr)) * 2048 + h * 64;
#pragma unroll
        for (int hdt = 0; hdt < 4; hdt++) {
            unsigned r0p = (unsigned)f2b(o[j][hdt][0] * inv) | ((unsigned)f2b(o[j][hdt][1] * inv) << 16);
            unsigned r1p = (unsigned)f2b(o[j][hdt][2] * inv) | ((unsigned)f2b(o[j][hdt][3] * inv) << 16);
            *(uint2*)(Ob + hdt * 16 + lq) = make_uint2(r0p, r1p);
        }
    }
}

// ---------------- launch ----------------
extern "C" void kernel_launch(void* const* d_in, const int* in_sizes, int n_in,
                              void* d_out, int out_size, void* d_ws, size_t ws_size,
                              hipStream_t stream) {
    (void)in_sizes; (void)n_in; (void)out_size; (void)ws_size;
    const float* x = (const float*)d_in[0];
    const float* cosT = (const float*)d_in[1];
    const float* sinT = (const float*)d_in[2];
    const float* Wq = (const float*)d_in[3];
    const float* Wk = (const float*)d_in[4];
    const float* Wv = (const float*)d_in[5];
    const float* Wo = (const float*)d_in[6];
    float* out = (float*)d_out;

    char* ws = (char*)d_ws;
    u16* Xb    = (u16*)(ws);                    // 16 MB
    u16* Wqkvt = (u16*)(ws + 16777216);         // 12 MB
    u16* Wot   = (u16*)(ws + 29360128);         // 8 MB
    u16* QKV   = (u16*)(ws + 37748736);         // 24 MB
    u16* Qh    = (u16*)(ws + 62914560);         // 16 MB
    u16* Kh    = (u16*)(ws + 79691776);         // 4 MB
    u16* Vt    = (u16*)(ws + 83886080);         // 4 MB (f16 bits)
    u16* Attn  = (u16*)(ws + 88080384);         // 16 MB

    cast_x_kernel<<<8192, 256, 0, stream>>>(x, Xb);
    wtrans_all_kernel<<<dim3(64, 64, 4), 256, 0, stream>>>(Wq, Wk, Wv, Wo, Wqkvt, Wot);

    gemm_qkv<<<192, 512, 0, stream>>>(Xb, Wqkvt, QKV);

    rope_kernel<<<20480, 256, 0, stream>>>(QKV, cosT, sinT, Qh, Kh);
    vtrans_kernel<<<512, 256, 0, stream>>>(QKV, Vt);

    flash_kernel<<<1024, 256, 0, stream>>>(Qh, Kh, Vt, Attn);

    gemm_out<<<256, 512, 0, stream>>>(Attn, Wot, out);
}

// Round 7
// 258.461 us; speedup vs baseline: 1.0532x; 1.0532x over previous
//
#include <hip/hip_runtime.h>

typedef unsigned short u16;
typedef __attribute__((ext_vector_type(8))) __bf16 bf16x8;
typedef __attribute__((ext_vector_type(4))) _Float16 f16x4;
typedef __attribute__((ext_vector_type(8))) _Float16 f16x8;
typedef __attribute__((ext_vector_type(4))) float f32x4;

#define BB 4
#define SS 1024
#define DD 2048
#define HH 32
#define KVHN 8
#define HDIM 64

__device__ __forceinline__ u16 f2b(float f) {
    union { float f; unsigned u; } v; v.f = f;
    unsigned r = v.u + 0x7FFFu + ((v.u >> 16) & 1u);
    return (u16)(r >> 16);
}
__device__ __forceinline__ float b2f(u16 h) {
    union { unsigned u; float f; } v; v.u = ((unsigned)h) << 16; return v.f;
}

__device__ __forceinline__ f32x4 mfma16(bf16x8 a, bf16x8 b, f32x4 c) {
    return __builtin_amdgcn_mfma_f32_16x16x32_bf16(a, b, c, 0, 0, 0);
}
__device__ __forceinline__ f32x4 mfma16h(f16x8 a, f16x8 b, f32x4 c) {
    return __builtin_amdgcn_mfma_f32_16x16x32_f16(a, b, c, 0, 0, 0);
}

__device__ __forceinline__ void async_cp16(const void* g, void* l) {
    __builtin_amdgcn_global_load_lds((__attribute__((address_space(1))) void*)g,
                                     (__attribute__((address_space(3))) void*)l,
                                     16, 0, 0);
}

// raw barrier WITHOUT the compiler's vmcnt(0) drain
__device__ __forceinline__ void block_sync() {
    asm volatile("" ::: "memory");
    __builtin_amdgcn_s_barrier();
    asm volatile("" ::: "memory");
}

// pack 8 floats -> f16x8 via v_cvt_pkrtz
__device__ __forceinline__ f16x8 pack8_f16(const float* p) {
    union { unsigned u[4]; f16x8 v; } pu;
    pu.u[0] = __builtin_bit_cast(unsigned, __builtin_amdgcn_cvt_pkrtz(p[0], p[1]));
    pu.u[1] = __builtin_bit_cast(unsigned, __builtin_amdgcn_cvt_pkrtz(p[2], p[3]));
    pu.u[2] = __builtin_bit_cast(unsigned, __builtin_amdgcn_cvt_pkrtz(p[4], p[5]));
    pu.u[3] = __builtin_bit_cast(unsigned, __builtin_amdgcn_cvt_pkrtz(p[6], p[7]));
    return pu.v;
}

// ---------------- prep: weight transposes (z<4) + x cast (z==4) in ONE launch ----------------
__global__ __launch_bounds__(256) void prep_kernel(const float* __restrict__ x,
                                                   const float* __restrict__ Wq,
                                                   const float* __restrict__ Wk,
                                                   const float* __restrict__ Wv,
                                                   const float* __restrict__ Wo,
                                                   u16* __restrict__ xb,
                                                   u16* __restrict__ Wqkvt,
                                                   u16* __restrict__ Wot) {
    __shared__ float tile[32][33];
    int z = blockIdx.z;
    int tid = threadIdx.x;
    if (z == 4) {
        // cast x: 4096 blocks x 256 thr x 8 f32
        int lb = blockIdx.y * 64 + blockIdx.x;
        int i = (lb * 256 + tid) * 8;
        float4 v0 = *(const float4*)(x + i);
        float4 v1 = *(const float4*)(x + i + 4);
        uint4 r;
        r.x = (unsigned)f2b(v0.x) | ((unsigned)f2b(v0.y) << 16);
        r.y = (unsigned)f2b(v0.z) | ((unsigned)f2b(v0.w) << 16);
        r.z = (unsigned)f2b(v1.x) | ((unsigned)f2b(v1.y) << 16);
        r.w = (unsigned)f2b(v1.z) | ((unsigned)f2b(v1.w) << 16);
        *(uint4*)(xb + i) = r;
        return;
    }
    const float* W = (z == 0) ? Wq : (z == 1) ? Wk : (z == 2) ? Wv : Wo;
    int N = (z == 1 || z == 2) ? 512 : 2048;
    int n_off = (z == 1) ? 2048 : (z == 2) ? 2560 : 0;
    u16* Wt = (z == 3) ? Wot : Wqkvt;
    int n0 = blockIdx.x * 32;
    if (n0 >= N) return;
    int k0 = blockIdx.y * 32;
    int nj = tid & 31;
    int ki = tid >> 5;
#pragma unroll
    for (int it = 0; it < 4; it++) {
        int kk = it * 8 + ki;
        tile[kk][nj] = W[(size_t)(k0 + kk) * N + n0 + nj];
    }
    __syncthreads();
#pragma unroll
    for (int it = 0; it < 4; it++) {
        int nn = it * 8 + ki;
        Wt[(size_t)(n0 + nn + n_off) * 2048 + k0 + nj] = f2b(tile[nj][nn]);
    }
}

// ============================================================================
// GEMM (qkv): C[4096][3072](bf16) = A[4096][2048] * Bt[3072][2048]^T
// Round-6 VERIFIED 8-phase quadrant template (unchanged).
// ============================================================================
__global__ __launch_bounds__(512, 2) void gemm_qkv(const u16* __restrict__ A,
                                                   const u16* __restrict__ Bt,
                                                   u16* __restrict__ C) {
    __shared__ __align__(16) u16 Ls[2][32768];
    const int tid = threadIdx.x;
    const int lane = tid & 63;
    const int w = tid >> 6;

    const int bid = blockIdx.x;
    const int xcd = bid & 7;
    const int loc = bid >> 3;
    const int mt = (xcd & 3) * 4 + (loc & 3);    // 0..15
    const int nt = (xcd >> 2) * 6 + (loc >> 2);  // 0..11
    const int m0 = mt * 256;
    const int n0 = nt * 256;

    const int wm_h = w >> 2;
    const int wn = (w & 3) * 64;
    const int lr = lane & 15;
    const int lg = lane >> 4;

    const int sr = lane >> 3;
    const int sl = (lane & 7) ^ (sr & 7);
    const u16* pA = A + (size_t)(m0 + w * 8 + sr) * 2048 + sl * 8;
    const u16* pB = Bt + (size_t)(n0 + w * 8 + sr) * 2048 + sl * 8;

#define STA(buf_, h_, kt_)                                                               \
    {                                                                                    \
        async_cp16(pA + (size_t)((h_) * 128) * 2048 + (kt_) * 64, &Ls[buf_][(h_) * 8192 + w * 512]);            \
        async_cp16(pA + (size_t)((h_) * 128 + 64) * 2048 + (kt_) * 64, &Ls[buf_][(h_) * 8192 + 4096 + w * 512]); \
    }
#define STB(buf_, h_, kt_)                                                               \
    {                                                                                    \
        async_cp16(pB + (size_t)((h_) * 128) * 2048 + (kt_) * 64, &Ls[buf_][16384 + (h_) * 8192 + w * 512]);            \
        async_cp16(pB + (size_t)((h_) * 128 + 64) * 2048 + (kt_) * 64, &Ls[buf_][16384 + (h_) * 8192 + 4096 + w * 512]); \
    }

    f32x4 acc[8][4];
    const f32x4 zero4 = {0.f, 0.f, 0.f, 0.f};
#pragma unroll
    for (int i = 0; i < 8; i++)
#pragma unroll
        for (int j = 0; j < 4; j++) acc[i][j] = zero4;

    bf16x8 af[8], b0[4], b1[4];

#define LDA(mh_, buf_)                                                                   \
    _Pragma("unroll") for (int mi = 0; mi < 4; mi++) _Pragma("unroll") for (int ks = 0; ks < 2; ks++) { \
        int rh = (mh_) * 64 + mi * 16 + lr;                                              \
        af[mi * 2 + ks] = *(const bf16x8*)(&Ls[buf_][wm_h * 8192 + rh * 64 + (((ks * 4 + lg) ^ (lr & 7)) * 8)]); \
    }
#define LDB(dst_, nh_, buf_)                                                             \
    _Pragma("unroll") for (int ni = 0; ni < 2; ni++) _Pragma("unroll") for (int ks = 0; ks < 2; ks++) { \
        int rowb = wn + (nh_) * 32 + ni * 16 + lr;                                       \
        dst_[ni * 2 + ks] = *(const bf16x8*)(&Ls[buf_][16384 + (rowb >> 7) * 8192 + (rowb & 127) * 64 + (((ks * 4 + lg) ^ (lr & 7)) * 8)]); \
    }
#define QMM(mh_, nh_, bb_)                                                               \
    __builtin_amdgcn_s_setprio(1);                                                       \
    _Pragma("unroll") for (int mi = 0; mi < 4; mi++) _Pragma("unroll") for (int ni = 0; ni < 2; ni++) { \
        acc[(mh_) * 4 + mi][(nh_) * 2 + ni] = mfma16(af[mi * 2 + 0], bb_[ni * 2 + 0], acc[(mh_) * 4 + mi][(nh_) * 2 + ni]); \
        acc[(mh_) * 4 + mi][(nh_) * 2 + ni] = mfma16(af[mi * 2 + 1], bb_[ni * 2 + 1], acc[(mh_) * 4 + mi][(nh_) * 2 + ni]); \
    }                                                                                    \
    __builtin_amdgcn_s_setprio(0);
#define WAITLDS                                                                          \
    asm volatile("s_waitcnt lgkmcnt(0)" ::: "memory");                                   \
    __builtin_amdgcn_sched_barrier(0);

    STA(0, 0, 0); STA(0, 1, 0); STB(0, 0, 0); STB(0, 1, 0);
    STB(1, 0, 1); STB(1, 1, 1);
    asm volatile("s_waitcnt vmcnt(0)" ::: "memory");
    block_sync();

#pragma unroll 1
    for (int I = 0; I < 16; ++I) {
        const int tb = 2 * I + 1;
        const int ta2 = (2 * I + 2) & 31;
        const int tb2 = (2 * I + 3) & 31;

        LDA(0, 0); LDB(b0, 0, 0);
        STA(1, 0, tb);
        block_sync(); WAITLDS;
        QMM(0, 0, b0);
        block_sync();

        LDB(b1, 1, 0);
        STA(1, 1, tb);
        block_sync(); WAITLDS;
        QMM(0, 1, b1);
        block_sync();

        LDA(1, 0);
        STB(0, 0, ta2);
        block_sync(); WAITLDS;
        QMM(1, 1, b1);
        block_sync();

        STB(0, 1, ta2);
        block_sync(); WAITLDS;
        QMM(1, 0, b0);
        asm volatile("s_waitcnt vmcnt(4)" ::: "memory");
        block_sync();

        LDA(0, 1); LDB(b0, 0, 1);
        STA(0, 0, ta2);
        block_sync(); WAITLDS;
        QMM(0, 0, b0);
        block_sync();

        LDB(b1, 1, 1);
        STA(0, 1, ta2);
        block_sync(); WAITLDS;
        QMM(0, 1, b1);
        block_sync();

        LDA(1, 1);
        STB(1, 0, tb2);
        block_sync(); WAITLDS;
        QMM(1, 1, b1);
        block_sync();

        STB(1, 1, tb2);
        block_sync(); WAITLDS;
        QMM(1, 0, b0);
        asm volatile("s_waitcnt vmcnt(4)" ::: "memory");
        block_sync();
    }
    asm volatile("s_waitcnt vmcnt(0)" ::: "memory");

    const int lq = lg * 4;
    const int wm = wm_h * 128;
#pragma unroll
    for (int mi = 0; mi < 8; mi++)
#pragma unroll
        for (int ni = 0; ni < 4; ni++)
#pragma unroll
            for (int i = 0; i < 4; i++) {
                int r = m0 + wm + mi * 16 + lq + i;
                int c = n0 + wn + ni * 16 + lr;
                C[(size_t)r * 3072 + c] = f2b(acc[mi][ni][i]);
            }
#undef STA
#undef STB
#undef LDA
#undef LDB
#undef QMM
#undef WAITLDS
}

// ============================================================================
// GEMM (out): C[4096][2048](f32) = A[4096][2048](bf16) * Bt[2048][2048]^T
// Round-4 VERIFIED version (k-slice 2-phase, vmcnt(3)). Unchanged.
// ============================================================================
__global__ __launch_bounds__(512, 2) void gemm_out(const u16* __restrict__ A,
                                                   const u16* __restrict__ Bt,
                                                   float* __restrict__ C) {
    __shared__ __align__(16) u16 Ls[2][24576];
    const int tid = threadIdx.x;
    const int lane = tid & 63;
    const int w = tid >> 6;

    const int bid = blockIdx.x;
    const int xcd = bid & 7;
    const int loc = bid >> 3;
    const int mt = (xcd & 3) * 4 + (loc & 3);
    const int nt = (xcd >> 2) * 8 + (loc >> 2);
    const int m0 = mt * 256;
    const int n0 = nt * 128;

    const int wm = (w >> 2) * 128;
    const int wn = (w & 3) * 32;
    const int lr = lane & 15;
    const int lg = lane >> 4;

    const int row0 = tid >> 2;
    const int g = tid & 3;
    const int sg = g ^ ((row0 >> 1) & 3);
    const u16* pA0 = A + (size_t)(m0 + row0) * 2048 + sg * 8;
    const u16* pA1 = pA0 + (size_t)128 * 2048;
    const u16* pB0 = Bt + (size_t)(n0 + row0) * 2048 + sg * 8;

#define OSTA(buf_, ks_, T_)                                                     \
    {                                                                           \
        async_cp16(pA0 + (T_) * 64 + (ks_) * 32, &Ls[buf_][(ks_) * 8192 + w * 512]);        \
        async_cp16(pA1 + (T_) * 64 + (ks_) * 32, &Ls[buf_][(ks_) * 8192 + 4096 + w * 512]); \
    }
#define OSTB(buf_, ks_, T_)                                                     \
    {                                                                           \
        async_cp16(pB0 + (T_) * 64 + (ks_) * 32, &Ls[buf_][16384 + (ks_) * 4096 + w * 512]); \
    }

    f32x4 acc[8][2];
    const f32x4 zero4 = {0.f, 0.f, 0.f, 0.f};
#pragma unroll
    for (int i = 0; i < 8; i++)
#pragma unroll
        for (int j = 0; j < 2; j++) acc[i][j] = zero4;

    bf16x8 af[8], bfr[2];

#define OLDA(ks_)                                                               \
    _Pragma("unroll") for (int mi = 0; mi < 8; mi++) {                          \
        int r_ = wm + mi * 16 + lr;                                             \
        af[mi] = *(const bf16x8*)(&Ls[cur][(ks_) * 8192 + r_ * 32 + ((lg ^ ((r_ >> 1) & 3)) * 8)]); \
    }
#define OLDB(ks_)                                                               \
    _Pragma("unroll") for (int ni = 0; ni < 2; ni++) {                          \
        int r_ = wn + ni * 16 + lr;                                             \
        bfr[ni] = *(const bf16x8*)(&Ls[cur][16384 + (ks_) * 4096 + r_ * 32 + ((lg ^ ((r_ >> 1) & 3)) * 8)]); \
    }
#define OMM                                                                     \
    __builtin_amdgcn_s_setprio(1);                                              \
    _Pragma("unroll") for (int mi = 0; mi < 8; mi++) _Pragma("unroll") for (int ni = 0; ni < 2; ni++) { \
        acc[mi][ni] = mfma16(af[mi], bfr[ni], acc[mi][ni]);                     \
    }                                                                           \
    __builtin_amdgcn_s_setprio(0);
#define OWAITMM                                                                 \
    asm volatile("s_waitcnt lgkmcnt(0)" ::: "memory");                          \
    __builtin_amdgcn_sched_barrier(0);

    OSTA(0, 0, 0); OSTB(0, 0, 0); OSTA(0, 1, 0); OSTB(0, 1, 0);
    OSTA(1, 0, 1); OSTB(1, 0, 1);
    asm volatile("s_waitcnt vmcnt(3)" ::: "memory");
    block_sync();

#pragma unroll 2
    for (int T = 0; T < 32; ++T) {
        const int cur = T & 1;
        const int oth = cur ^ 1;
        const int Tp1 = (T + 1) & 31;
        const int Tp2 = (T + 2) & 31;

        OLDA(0); OLDB(0);
        OSTA(oth, 1, Tp1); OSTB(oth, 1, Tp1);
        block_sync(); OWAITMM;
        OMM;
        block_sync();

        OLDA(1); OLDB(1);
        OSTA(cur, 0, Tp2); OSTB(cur, 0, Tp2);
        block_sync(); OWAITMM;
        OMM;
        asm volatile("s_waitcnt vmcnt(3)" ::: "memory");
        block_sync();
    }
    asm volatile("s_waitcnt vmcnt(0)" ::: "memory");

    const int lq = lg * 4;
#pragma unroll
    for (int mi = 0; mi < 8; mi++)
#pragma unroll
        for (int ni = 0; ni < 2; ni++)
#pragma unroll
            for (int i = 0; i < 4; i++) {
                int r = m0 + wm + mi * 16 + lq + i;
                int c = n0 + wn + ni * 16 + lr;
                C[(size_t)r * 2048 + c] = acc[mi][ni][i];
            }
#undef OSTA
#undef OSTB
#undef OLDA
#undef OLDB
#undef OMM
#undef OWAITMM
}

// ---------------- RoPE + reshape (bid<20480) + V transpose (bid>=20480), ONE launch.
// Q pre-scaled by 0.125*log2(e). K rows permuted within each 32-seq block:
// row = (s&~31) + (rr>=4)*16 + ((s>>3)&3)*4 + (rr&3), rr = s&7.
__global__ __launch_bounds__(256) void ropevt_kernel(const u16* __restrict__ QKV,
                                                     const float* __restrict__ cosT,
                                                     const float* __restrict__ sinT,
                                                     u16* __restrict__ Qh,
                                                     u16* __restrict__ Kh,
                                                     u16* __restrict__ Vt) {
    __shared__ u16 tile[64][65];
    const int bid = blockIdx.x;
    const int tid = threadIdx.x;
    if (bid < 20480) {
        const float QSC = 0.125f * 1.44269504088896f;
        int idx = bid * 256 + tid;
        int d = idx & 31;
        int t = idx >> 5;
        int hh = t % 40;
        int row = t / 40;
        int s = row & (SS - 1);
        int b = row >> 10;
        float c = cosT[s * HDIM + d];
        float sn = sinT[s * HDIM + d];
        if (hh < 32) {
            const u16* src = QKV + (size_t)row * 3072 + hh * 64 + d;
            float x1 = b2f(src[0]), x2 = b2f(src[32]);
            u16* dst = Qh + ((size_t)(b * HH + hh) * SS + s) * 64 + d;
            dst[0] = f2b((x1 * c - x2 * sn) * QSC);
            dst[32] = f2b((x2 * c + x1 * sn) * QSC);
        } else {
            int g = hh - 32;
            const u16* src = QKV + (size_t)row * 3072 + 2048 + g * 64 + d;
            float x1 = b2f(src[0]), x2 = b2f(src[32]);
            int rr = s & 7;
            int kpos = (s & ~31) + ((rr >= 4) ? 16 : 0) + ((s >> 3) & 3) * 4 + (rr & 3);
            u16* dst = Kh + ((size_t)(b * KVHN + g) * SS + kpos) * 64 + d;
            dst[0] = f2b(x1 * c - x2 * sn);
            dst[32] = f2b(x2 * c + x1 * sn);
        }
        return;
    }
    // V transpose: QKV bf16 -> Vt[B][KVH][64][S] f16
    int blk = bid - 20480;
    int st = blk & 15;
    int t2 = blk >> 4;
    int g = t2 & 7;
    int b = t2 >> 3;
    int cj = tid & 63;
    int ri = tid >> 6;
    const u16* src = QKV + ((size_t)(b * SS + st * 64)) * 3072 + 2560 + g * 64;
#pragma unroll
    for (int it = 0; it < 16; it++) {
        int s_i = it * 4 + ri;
        tile[s_i][cj] = src[(size_t)s_i * 3072 + cj];
    }
    __syncthreads();
    u16* dst = Vt + ((size_t)(b * KVHN + g) * HDIM) * SS + st * 64;
#pragma unroll
    for (int it = 0; it < 16; it++) {
        int hd_i = it * 4 + ri;
        _Float16 hv = (_Float16)b2f(tile[cj][hd_i]);
        union { _Float16 h; u16 u; } cv; cv.h = hv;
        dst[(size_t)hd_i * SS + cj] = cv.u;
    }
}

// ---------------- Flash attention: 64 q-rows/block (2x K/V reuse), K=32 PV, LDS-staged K/V ----
// 1-D grid 512 (2 blocks/CU), 256 threads. XCD decode: each XCD owns 4 (b,g) KV-sets.
__global__ __launch_bounds__(256, 2) void flash_kernel(const u16* __restrict__ Qh,
                                                       const u16* __restrict__ Kh,
                                                       const u16* __restrict__ Vt,
                                                       u16* __restrict__ Attn) {
    __shared__ __align__(16) u16 Kls[2][4096];
    __shared__ __align__(16) u16 Vls[2][4096];
    const int tid = threadIdx.x;
    const int lane = tid & 63;
    const int w = tid >> 6;
    const int bid = blockIdx.x;
    const int gbp = ((bid & 7) << 2) | ((bid >> 3) & 3);  // XCD-chunked (b,g) pair
    const int qt2 = bid >> 5;                              // 64-row q-tile [0,16)
    const int g = gbp & 7;
    const int b = gbp >> 3;
    const int h = g * 4 + w;
    const int lr = lane & 15;
    const int lg = lane >> 4;
    const int lk8 = lg * 8;
    const int lq = lg * 4;

    const u16* Qbase = Qh + ((size_t)(b * HH + h) * SS + qt2 * 64) * HDIM;
    bf16x8 qb[4][2];
#pragma unroll
    for (int j = 0; j < 4; j++) {
        qb[j][0] = *(const bf16x8*)(Qbase + (size_t)(j * 16 + lr) * HDIM + lk8);
        qb[j][1] = *(const bf16x8*)(Qbase + (size_t)(j * 16 + lr) * HDIM + 32 + lk8);
    }

    const u16* Kbase = Kh + (size_t)(b * KVHN + g) * SS * HDIM;
    const u16* Vbase = Vt + (size_t)(b * KVHN + g) * HDIM * SS;

    const int r0 = tid >> 3;
    const int c0 = tid & 7;

    const f32x4 zero4 = {0.f, 0.f, 0.f, 0.f};
    const f32x4 initS = {-4.f, -4.f, -4.f, -4.f};
    f32x4 o[4][4];
    float lsum[4] = {0.f, 0.f, 0.f, 0.f};
#pragma unroll
    for (int j = 0; j < 4; j++)
#pragma unroll
        for (int i = 0; i < 4; i++) o[j][i] = zero4;

#define STAGE(kt, p)                                                              \
    {                                                                             \
        _Pragma("unroll") for (int sh = 0; sh < 2; sh++) {                        \
            int rr = r0 + sh * 32;                                                \
            int cs = c0 ^ (rr & 7);                                              \
            async_cp16(Kbase + (size_t)((kt) + rr) * HDIM + cs * 8,               \
                       &Kls[p][sh * 2048 + w * 512]);                             \
            async_cp16(Vbase + (size_t)rr * SS + (kt) + cs * 8,                   \
                       &Vls[p][sh * 2048 + w * 512]);                             \
        }                                                                         \
    }

    STAGE(0, 0);
    __syncthreads();

    for (int t = 0; t < 16; t++) {
        const int p = t & 1;
        if (t < 15) STAGE((t + 1) * 64, p ^ 1);

#pragma unroll
        for (int c = 0; c < 2; c++) {  // two 32-kv chunks per 64-tile
            f32x4 s[2][4];  // [half][j]
#pragma unroll
            for (int halfi = 0; halfi < 2; halfi++) {
                const int R = c * 32 + halfi * 16 + lr;
                const u16* kr = &Kls[p][R * 64];
                bf16x8 kb0 = *(const bf16x8*)(kr + ((lg ^ (R & 7)) * 8));
                bf16x8 kb1 = *(const bf16x8*)(kr + (((4 + lg) ^ (R & 7)) * 8));
#pragma unroll
                for (int j = 0; j < 4; j++) {
                    f32x4 a = initS;
                    a = mfma16(kb0, qb[j][0], a);
                    a = mfma16(kb1, qb[j][1], a);
                    s[halfi][j] = a;
                }
            }

            f16x8 va[4];
#pragma unroll
            for (int hdt = 0; hdt < 4; hdt++) {
                const int R2 = hdt * 16 + lr;
                va[hdt] = *(const f16x8*)(&Vls[p][R2 * 64 + (((c * 4 + lg) ^ (R2 & 7)) * 8)]);
            }

#pragma unroll
            for (int j = 0; j < 4; j++) {
                float pv[8];
#pragma unroll
                for (int r = 0; r < 4; r++) {
                    pv[r] = __builtin_amdgcn_exp2f(s[0][j][r]);
                    pv[4 + r] = __builtin_amdgcn_exp2f(s[1][j][r]);
                }
                lsum[j] += ((pv[0] + pv[1]) + (pv[2] + pv[3])) +
                           ((pv[4] + pv[5]) + (pv[6] + pv[7]));
                f16x8 pb = pack8_f16(pv);
#pragma unroll
                for (int hdt = 0; hdt < 4; hdt++)
                    o[j][hdt] = mfma16h(va[hdt], pb, o[j][hdt]);
            }
        }
        __syncthreads();
    }

#pragma unroll
    for (int j = 0; j < 4; j++) {
        float su = lsum[j];
        su += __shfl_xor(su, 16);
        su += __shfl_xor(su, 32);
        float inv = 1.f / su;
        u16* Ob = Attn + ((size_t)(b * SS + qt2 * 64 + j * 16 + lr)) * 2048 + h * 64;
#pragma unroll
        for (int hdt = 0; hdt < 4; hdt++) {
            unsigned r0p = (unsigned)f2b(o[j][hdt][0] * inv) | ((unsigned)f2b(o[j][hdt][1] * inv) << 16);
            unsigned r1p = (unsigned)f2b(o[j][hdt][2] * inv) | ((unsigned)f2b(o[j][hdt][3] * inv) << 16);
            *(uint2*)(Ob + hdt * 16 + lq) = make_uint2(r0p, r1p);
        }
    }
}

// ---------------- launch ----------------
extern "C" void kernel_launch(void* const* d_in, const int* in_sizes, int n_in,
                              void* d_out, int out_size, void* d_ws, size_t ws_size,
                              hipStream_t stream) {
    (void)in_sizes; (void)n_in; (void)out_size; (void)ws_size;
    const float* x = (const float*)d_in[0];
    const float* cosT = (const float*)d_in[1];
    const float* sinT = (const float*)d_in[2];
    const float* Wq = (const float*)d_in[3];
    const float* Wk = (const float*)d_in[4];
    const float* Wv = (const float*)d_in[5];
    const float* Wo = (const float*)d_in[6];
    float* out = (float*)d_out;

    char* ws = (char*)d_ws;
    u16* Xb    = (u16*)(ws);                    // 16 MB
    u16* Wqkvt = (u16*)(ws + 16777216);         // 12 MB
    u16* Wot   = (u16*)(ws + 29360128);         // 8 MB
    u16* QKV   = (u16*)(ws + 37748736);         // 24 MB
    u16* Qh    = (u16*)(ws + 62914560);         // 16 MB
    u16* Kh    = (u16*)(ws + 79691776);         // 4 MB
    u16* Vt    = (u16*)(ws + 83886080);         // 4 MB (f16 bits)
    u16* Attn  = (u16*)(ws + 88080384);         // 16 MB

    prep_kernel<<<dim3(64, 64, 5), 256, 0, stream>>>(x, Wq, Wk, Wv, Wo, Xb, Wqkvt, Wot);

    gemm_qkv<<<192, 512, 0, stream>>>(Xb, Wqkvt, QKV);

    ropevt_kernel<<<20992, 256, 0, stream>>>(QKV, cosT, sinT, Qh, Kh, Vt);

    flash_kernel<<<512, 256, 0, stream>>>(Qh, Kh, Vt, Attn);

    gemm_out<<<256, 512, 0, stream>>>(Attn, Wot, out);
}